// Round 19
// baseline (179.629 us; speedup 1.0000x reference)
//
#include <hip/hip_runtime.h>
#include <hip/hip_bf16.h>
#include <cstddef>
#include <cstdint>

// Problem constants: B=16, CIN=COUT=64, HID=32, H=W=32, K=5, PAD=2
#define NTOK 1024      // H*W
#define NB   16        // batch
#define NC   64        // channels (CIN == COUT)
#define NHID 32        // attention hidden

// padded conv input: pad[b][kh][36*36 px][64 c] bf16
#define PAD_BSTRIDE 165888   // 2*1296*64
#define PAD_KSTRIDE 82944    // 1296*64

typedef __attribute__((ext_vector_type(8))) short short8;   // 8 bf16 = 4 VGPR (MFMA A/B frag)
typedef __attribute__((ext_vector_type(4))) float f32x4;    // MFMA acc frag / native v4f

// round-to-nearest-even f32 -> bf16 (as raw ushort)
__device__ __forceinline__ ushort f2b(float f) {
  uint32_t u = __builtin_bit_cast(uint32_t, f);
  return (ushort)((u + 0x7FFFu + ((u >> 16) & 1u)) >> 16);
}
__device__ __forceinline__ float b2f(ushort u) {
  return __builtin_bit_cast(float, (uint32_t)u << 16);
}
// 8 consecutive f32 -> bf16x8 frag
__device__ __forceinline__ short8 ldw8(const float* __restrict__ p) {
  float4 f0 = *(const float4*)p, f1 = *(const float4*)(p + 4);
  short8 r;
  r[0] = (short)f2b(f0.x); r[1] = (short)f2b(f0.y);
  r[2] = (short)f2b(f0.z); r[3] = (short)f2b(f0.w);
  r[4] = (short)f2b(f1.x); r[5] = (short)f2b(f1.y);
  r[6] = (short)f2b(f1.z); r[7] = (short)f2b(f1.w);
  return r;
}
__device__ __forceinline__ float sigm(float x) { return 1.f / (1.f + __expf(-x)); }
__device__ __forceinline__ float tanh_fast(float x) {
  float e = __expf(2.f * x);
  return 1.f - 2.f / (e + 1.f);   // safe at +/-inf
}

// ---- PREP: fused {h transpose -> pad kh1 interior | pad ring zero | weight
// pre-pass}. Grid (18, NB): x<16 tpose blocks, x==16 ring-zero, x==17 wpre slice.
__global__ __launch_bounds__(256) void prep_kernel(
    const float* __restrict__ h, const float* __restrict__ W,
    ushort* __restrict__ pad, ushort* __restrict__ Wb) {
  __shared__ float tile[64][65];
  int bx = blockIdx.x, b = blockIdx.y, t = threadIdx.x;
  if (bx < 16) {
    int n0 = bx * 64;
    const float* s = h + (size_t)b * NC * NTOK;
#pragma unroll
    for (int r = 0; r < 4; ++r) {
      int c = r * 16 + (t >> 4);
      int nl = (t & 15) * 4;
      float4 v = *(const float4*)(s + (size_t)c * NTOK + n0 + nl);
      tile[c][nl] = v.x; tile[c][nl + 1] = v.y; tile[c][nl + 2] = v.z; tile[c][nl + 3] = v.w;
    }
    __syncthreads();
    int tok = t >> 2, c0 = (t & 3) * 16;
    __attribute__((aligned(16))) ushort tmp[16];
#pragma unroll
    for (int i = 0; i < 16; ++i) tmp[i] = f2b(tile[c0 + i][tok]);
    int gtok = n0 + tok;
    ushort* d = pad + (size_t)b * PAD_BSTRIDE + PAD_KSTRIDE +
                ((gtok >> 5) + 2) * 2304 + ((gtok & 31) + 2) * 64 + c0;
    *(uint4*)(d)     = *(const uint4*)(tmp);
    *(uint4*)(d + 8) = *(const uint4*)(tmp + 8);
  } else if (bx == 16) {
    // zero the 272-px ring of both kh windows for batch b
    ushort* pb = pad + (size_t)b * PAD_BSTRIDE;
    for (int i = t; i < 2 * 2176; i += 256) {   // 2176 = 272 px * 8 chunks
      int kh = i >= 2176;
      int j = i - kh * 2176;
      int r = j >> 3, e = j & 7;
      int row, col;
      if (r < 144) { int r2 = r / 36; row = (r2 < 2) ? r2 : r2 + 32; col = r - r2 * 36; }
      else { int rr = r - 144; row = 2 + (rr >> 2); int cm = rr & 3; col = (cm < 2) ? cm : cm + 32; }
      *(uint4*)(pb + (size_t)kh * PAD_KSTRIDE + (size_t)(row * 36 + col) * 64 + e * 8) =
          make_uint4(0u, 0u, 0u, 0u);
    }
  } else {
    // weight pre-pass slice: oc in [b*16, b*16+16), all 128 ic
    for (int i = t; i < 2048; i += 256) {
      int oc = b * 16 + (i >> 7), ic = i & 127;
      const float* src = W + ((size_t)oc * 128 + ic) * 25;
#pragma unroll
      for (int kk = 0; kk < 25; ++kk)
        Wb[((size_t)oc * 25 + kk) * 128 + ic] = f2b(src[kk]);
    }
  }
}

// ---- fused transpose + q,k,v projection via MFMA (reads f32 channel-major x).
__global__ __launch_bounds__(256) void qkvproj_kernel(
    const float* __restrict__ x, const float* __restrict__ Wq,
    const float* __restrict__ Wk, const float* __restrict__ Wv,
    ushort* __restrict__ qT, ushort* __restrict__ kT, ushort* __restrict__ vb) {
  __shared__ float tile[64][65];
  __shared__ ushort xb[64][72];
  __shared__ ushort sq[64][32], sk[64][32];
  int t = threadIdx.x, wave = t >> 6, lane = t & 63;
  int lo = lane & 15, lg = lane >> 4;
  int n0 = blockIdx.x * 64, b = blockIdx.y;
  const float* s = x + (size_t)b * NC * NTOK;
#pragma unroll
  for (int r = 0; r < 4; ++r) {
    int c = r * 16 + (t >> 4);
    int nl = (t & 15) * 4;
    float4 v = *(const float4*)(s + (size_t)c * NTOK + n0 + nl);
    tile[c][nl] = v.x; tile[c][nl + 1] = v.y; tile[c][nl + 2] = v.z; tile[c][nl + 3] = v.w;
  }
  __syncthreads();
  {
    int tok = t >> 2, c0 = (t & 3) * 16;
    __attribute__((aligned(16))) ushort tmp[16];
#pragma unroll
    for (int i = 0; i < 16; ++i) tmp[i] = f2b(tile[c0 + i][tok]);
    *(uint4*)(&xb[tok][c0])     = *(const uint4*)(tmp);
    *(uint4*)(&xb[tok][c0 + 8]) = *(const uint4*)(tmp + 8);
  }
  __syncthreads();
  const ushort* xrow = &xb[wave * 16 + lo][8 * lg];
  short8 a0 = *(const short8*)(xrow);
  short8 a1 = *(const short8*)(xrow + 32);
  f32x4 aq[2], ak[2];
#pragma unroll
  for (int dg = 0; dg < 2; ++dg) {
    short8 wq0 = ldw8(Wq + (size_t)(dg * 16 + lo) * NC + 8 * lg);
    short8 wq1 = ldw8(Wq + (size_t)(dg * 16 + lo) * NC + 32 + 8 * lg);
    short8 wk0 = ldw8(Wk + (size_t)(dg * 16 + lo) * NC + 8 * lg);
    short8 wk1 = ldw8(Wk + (size_t)(dg * 16 + lo) * NC + 32 + 8 * lg);
    f32x4 z = {0.f, 0.f, 0.f, 0.f};
    aq[dg] = __builtin_amdgcn_mfma_f32_16x16x32_bf16(a0, wq0, z, 0, 0, 0);
    aq[dg] = __builtin_amdgcn_mfma_f32_16x16x32_bf16(a1, wq1, aq[dg], 0, 0, 0);
    ak[dg] = __builtin_amdgcn_mfma_f32_16x16x32_bf16(a0, wk0, z, 0, 0, 0);
    ak[dg] = __builtin_amdgcn_mfma_f32_16x16x32_bf16(a1, wk1, ak[dg], 0, 0, 0);
  }
  f32x4 av[4];
#pragma unroll
  for (int g = 0; g < 4; ++g) {
    short8 wv0 = ldw8(Wv + (size_t)(g * 16 + lo) * NC + 8 * lg);
    short8 wv1 = ldw8(Wv + (size_t)(g * 16 + lo) * NC + 32 + 8 * lg);
    f32x4 z = {0.f, 0.f, 0.f, 0.f};
    av[g] = __builtin_amdgcn_mfma_f32_16x16x32_bf16(wv0, a0, z, 0, 0, 0);
    av[g] = __builtin_amdgcn_mfma_f32_16x16x32_bf16(wv1, a1, av[g], 0, 0, 0);
  }
#pragma unroll
  for (int dg = 0; dg < 2; ++dg)
#pragma unroll
    for (int r = 0; r < 4; ++r) {
      sq[wave * 16 + 4 * lg + r][dg * 16 + lo] = f2b(aq[dg][r]);
      sk[wave * 16 + 4 * lg + r][dg * 16 + lo] = f2b(ak[dg][r]);
    }
  ushort* vbase = vb + (size_t)b * NC * NTOK + n0 + wave * 16 + lo;
#pragma unroll
  for (int g = 0; g < 4; ++g)
#pragma unroll
    for (int r = 0; r < 4; ++r)
      vbase[(size_t)(g * 16 + lg * 4 + r) * NTOK] = f2b(av[g][r]);
  __syncthreads();
  int tok = t >> 2, d0 = (t & 3) * 8;
  size_t base = ((size_t)b * NTOK + n0 + tok) * NHID + d0;
  *(short8*)(qT + base) = *(const short8*)(&sq[tok][d0]);
  *(short8*)(kT + base) = *(const short8*)(&sk[tok][d0]);
}

// ---- FUSED attention: scores (MFMA) -> softmax -> S->bf16 LDS -> coalesced
// NONTEMPORAL atten write (ATTN2) -> PV (MFMA, 2-chain) -> residual epilogue.
#define SP 1048   // S-LDS pitch (ushorts): bank stride 12 -> <=2-way
template <bool ATTN2>
__global__ __launch_bounds__(256) void attn_fused_kernel(
    const ushort* __restrict__ qT, const ushort* __restrict__ kT,
    const ushort* __restrict__ vb, const float* __restrict__ resid,
    float* __restrict__ attnf, float* __restrict__ outf,
    ushort* __restrict__ outb_pad, float scale) {
  __shared__ ushort s_lds[16 * SP];
  __shared__ float wmax[4][16], wsum[4][16];
  int t = threadIdx.x, wave = t >> 6, lane = t & 63;
  int lo = lane & 15, lg = lane >> 4;
  int n0 = blockIdx.x * 16, b = blockIdx.y;
  int m0 = wave * 256;
  short8 a = *(const short8*)(qT + ((size_t)b * NTOK + n0 + lo) * NHID + 8 * lg);
  f32x4 acc[16];
#pragma unroll
  for (int j = 0; j < 16; ++j) {
    short8 bf = *(const short8*)(kT + ((size_t)b * NTOK + m0 + j * 16 + lo) * NHID + 8 * lg);
    f32x4 z = {0.f, 0.f, 0.f, 0.f};
    acc[j] = __builtin_amdgcn_mfma_f32_16x16x32_bf16(a, bf, z, 0, 0, 0);
  }
  float pm[4];
#pragma unroll
  for (int r = 0; r < 4; ++r) {
    float m = acc[0][r];
#pragma unroll
    for (int j = 1; j < 16; ++j) m = fmaxf(m, acc[j][r]);
#pragma unroll
    for (int off = 1; off < 16; off <<= 1) m = fmaxf(m, __shfl_xor(m, off, 64));
    pm[r] = m;
  }
  if (lo == 0)
#pragma unroll
    for (int r = 0; r < 4; ++r) wmax[wave][4 * lg + r] = pm[r];
  __syncthreads();
  float mr[4];
#pragma unroll
  for (int r = 0; r < 4; ++r)
    mr[r] = fmaxf(fmaxf(wmax[0][4 * lg + r], wmax[1][4 * lg + r]),
                  fmaxf(wmax[2][4 * lg + r], wmax[3][4 * lg + r]));
  float ps[4] = {0.f, 0.f, 0.f, 0.f};
#pragma unroll
  for (int j = 0; j < 16; ++j)
#pragma unroll
    for (int r = 0; r < 4; ++r) {
      float e = __expf(acc[j][r] - mr[r]);
      acc[j][r] = e;
      ps[r] += e;
    }
#pragma unroll
  for (int r = 0; r < 4; ++r)
#pragma unroll
    for (int off = 1; off < 16; off <<= 1) ps[r] += __shfl_xor(ps[r], off, 64);
  if (lo == 0)
#pragma unroll
    for (int r = 0; r < 4; ++r) wsum[wave][4 * lg + r] = ps[r];
  __syncthreads();
  float inv[4];
#pragma unroll
  for (int r = 0; r < 4; ++r)
    inv[r] = 1.f / (wsum[0][4 * lg + r] + wsum[1][4 * lg + r] +
                    wsum[2][4 * lg + r] + wsum[3][4 * lg + r]);
#pragma unroll
  for (int j = 0; j < 16; ++j)
#pragma unroll
    for (int r = 0; r < 4; ++r)
      s_lds[(4 * lg + r) * SP + m0 + j * 16 + lo] = f2b(acc[j][r] * inv[r]);
  __syncthreads();
  if constexpr (ATTN2) {
    // coalesced nontemporal f32 write (64MB stream, never re-read -> bypass L2)
    int ml = lane * 4;
    float* abase = attnf + ((size_t)b * NTOK + n0) * NTOK + m0;
#pragma unroll
    for (int n = 0; n < 16; ++n) {
      ushort4 sv = *(const ushort4*)(s_lds + n * SP + m0 + ml);
      f32x4 o = {b2f(sv.x), b2f(sv.y), b2f(sv.z), b2f(sv.w)};
      __builtin_nontemporal_store(o, (f32x4*)(abase + (size_t)n * NTOK + ml));
    }
  }
  int cb = wave * 16;
  const ushort* vbb = vb + ((size_t)b * NC + cb + lo) * NTOK;
  f32x4 acc2 = {0.f, 0.f, 0.f, 0.f}, acc3 = {0.f, 0.f, 0.f, 0.f};
  for (int ms = 0; ms < NTOK; ms += 64) {
    short8 af0 = *(const short8*)(s_lds + lo * SP + ms + 8 * lg);
    short8 bf0 = *(const short8*)(vbb + ms + 8 * lg);
    short8 af1 = *(const short8*)(s_lds + lo * SP + ms + 32 + 8 * lg);
    short8 bf1 = *(const short8*)(vbb + ms + 32 + 8 * lg);
    acc2 = __builtin_amdgcn_mfma_f32_16x16x32_bf16(af0, bf0, acc2, 0, 0, 0);
    acc3 = __builtin_amdgcn_mfma_f32_16x16x32_bf16(af1, bf1, acc3, 0, 0, 0);
  }
#pragma unroll
  for (int r = 0; r < 4; ++r) acc2[r] += acc3[r];
  int c = cb + lo;
  float4 rv = *(const float4*)(resid + ((size_t)b * NC + c) * NTOK + n0 + 4 * lg);
  float rvv[4] = {rv.x, rv.y, rv.z, rv.w};
  if constexpr (ATTN2) {
    float4 o;
    o.x = scale * (rvv[0] + acc2[0]); o.y = scale * (rvv[1] + acc2[1]);
    o.z = scale * (rvv[2] + acc2[2]); o.w = scale * (rvv[3] + acc2[3]);
    *(float4*)(outf + ((size_t)b * NC + c) * NTOK + n0 + 4 * lg) = o;
  } else {
#pragma unroll
    for (int r = 0; r < 4; ++r) {
      int tok = n0 + 4 * lg + r;
      float val = scale * (rvv[r] + acc2[r]);
      outb_pad[(size_t)b * PAD_BSTRIDE + ((tok >> 5) + 2) * 2304 +
               ((tok & 31) + 2) * 64 + c] = f2b(val);
    }
  }
}

// ---- FUSED conv + LSTM, BARRIER-FREE K-loop, depth-2 reg pipeline.
// K-steps reordered s = tap*2 + kh so weight offset = s*64 (pure affine).
// Both kh B-windows staged once (read-only -> zero in-loop barriers).
// wg = 4 waves = 128 gate-rows (32 ch x 4 gates, chh in grid) x 64 px.
// Per wave-step: 8 A global loads (L2, 1-step lookahead in wA/wB reg sets)
// + 4 B ds_reads + 16 MFMA. Grid (16 pt, 2 chh, 16 b) = 512 wgs.
// LDS 64.1 KB (B only) -> 2 wg/CU. LSTM fused in epilogue.
#define BP 76
__global__ __launch_bounds__(256, 2) void conv_lstm_kernel(
    const ushort* __restrict__ pad,   // [b][2][36*36][64] bf16
    const ushort* __restrict__ Wb,    // [256 oc][25 kk][128 ic] bf16
    const float* __restrict__ bias, const float* __restrict__ c_in,
    float* __restrict__ c_out, float* __restrict__ h_out) {
  __shared__ ushort ldsB[432 * BP];   // [2 kh][6 rows x 36 cols][64 ic]
  int t = threadIdx.x;
  int lane = t & 63, lo = lane & 15, lg = lane >> 4;
  int wid = t >> 6, cb = wid & 1, ph = wid >> 1;   // cb: 16-ch block, ph: px row
  int pt = blockIdx.x, chh = blockIdx.y, b = blockIdx.z;
  const ushort* pb = pad + (size_t)b * PAD_BSTRIDE + (size_t)(pt * 2) * 2304;

  // stage BOTH kh B-windows once (contiguous src, pre-padded zeros)
  for (int i = t; i < 3456; i += 256) {
    int pxw = i >> 3, ch8 = (i & 7) * 8;
    int kh = pxw >= 216, w = pxw - kh * 216;
    uint4 v = *(const uint4*)(pb + (size_t)kh * PAD_KSTRIDE + (size_t)w * 64 + ch8);
    *(uint4*)(ldsB + pxw * BP + ch8) = v;
  }

  // per-lane weight row bases: gate g -> Wb row g*64 + chh*32 + cb*16 + lo.
  // Step s weight offset = s*64 elements (kk = s>>1, kh = s&1: kk*128+kh*64).
  const ushort* wb0 = Wb + (size_t)(0 * 64 + chh * 32 + cb * 16 + lo) * 3200 + 8 * lg;
  const ushort* wb1 = Wb + (size_t)(1 * 64 + chh * 32 + cb * 16 + lo) * 3200 + 8 * lg;
  const ushort* wb2 = Wb + (size_t)(2 * 64 + chh * 32 + cb * 16 + lo) * 3200 + 8 * lg;
  const ushort* wb3 = Wb + (size_t)(3 * 64 + chh * 32 + cb * 16 + lo) * 3200 + 8 * lg;

#define LOADA(dst, sv)                                                         \
  {                                                                            \
    dst[0] = *(const short8*)(wb0 + (sv) * 64);                                \
    dst[1] = *(const short8*)(wb0 + (sv) * 64 + 32);                           \
    dst[2] = *(const short8*)(wb1 + (sv) * 64);                                \
    dst[3] = *(const short8*)(wb1 + (sv) * 64 + 32);                           \
    dst[4] = *(const short8*)(wb2 + (sv) * 64);                                \
    dst[5] = *(const short8*)(wb2 + (sv) * 64 + 32);                           \
    dst[6] = *(const short8*)(wb3 + (sv) * 64);                                \
    dst[7] = *(const short8*)(wb3 + (sv) * 64 + 32);                           \
  }
#define STEP(wreg, sv)                                                         \
  {                                                                            \
    int _kh = (sv) & 1;                                                        \
    int _tap = (sv) >> 1;                                                      \
    int _ky = _tap / 5, _kx = _tap - 5 * _ky;                                  \
    int _bb = (_kh * 216 + _ky * 36 + _kx) * BP;                               \
    _Pragma("unroll") for (int icc = 0; icc < 2; ++icc) {                      \
      short8 bf[2];                                                            \
      _Pragma("unroll") for (int j = 0; j < 2; ++j)                            \
        bf[j] = *(const short8*)(ldsB + _bb +                                  \
                 (ph * 36 + j * 16 + lo) * BP + icc * 32 + 8 * lg);            \
      _Pragma("unroll") for (int i = 0; i < 4; ++i)                            \
        _Pragma("unroll") for (int j = 0; j < 2; ++j)                          \
          acc[i][j] = __builtin_amdgcn_mfma_f32_16x16x32_bf16(                 \
              wreg[i * 2 + icc], bf[j], acc[i][j], 0, 0, 0);                   \
    }                                                                          \
  }

  short8 wA[8], wB[8];    // two named depth-2 pipeline buffers (static idx)
  LOADA(wA, 0);
  LOADA(wB, 1);

  f32x4 acc[4][2];
#pragma unroll
  for (int i = 0; i < 4; ++i)
#pragma unroll
    for (int j = 0; j < 2; ++j) acc[i][j] = {0.f, 0.f, 0.f, 0.f};

  __syncthreads();   // B windows staged; the ONLY barrier

  for (int s = 0; s < 48; s += 2) {
    STEP(wA, s);     LOADA(wA, s + 2);
    STEP(wB, s + 1); LOADA(wB, s + 3);   // s+3 <= 49
  }
  STEP(wA, 48);
  STEP(wB, 49);
#undef STEP
#undef LOADA

  // LSTM epilogue: thread holds gates i/f/o/g at (ch, p)
#pragma unroll
  for (int j = 0; j < 2; ++j)
#pragma unroll
    for (int r = 0; r < 4; ++r) {
      int ch = chh * 32 + cb * 16 + lg * 4 + r;
      int p = pt * 64 + ph * 32 + j * 16 + lo;
      size_t ci = ((size_t)b * NC + ch) * NTOK + p;
      float iv = sigm(acc[0][j][r] + bias[ch]);
      float fv = sigm(acc[1][j][r] + bias[64 + ch]);
      float ov = sigm(acc[2][j][r] + bias[128 + ch]);
      float gv = tanh_fast(acc[3][j][r] + bias[192 + ch]);
      float cn = fv * c_in[ci] + iv * gv;
      c_out[ci] = cn;
      h_out[ci] = ov * tanh_fast(cn);
    }
}

extern "C" void kernel_launch(void* const* d_in, const int* in_sizes, int n_in,
                              void* d_out, int out_size, void* d_ws, size_t ws_size,
                              hipStream_t stream) {
  const float* x      = (const float*)d_in[0];
  const float* h      = (const float*)d_in[1];
  const float* c      = (const float*)d_in[2];
  const float* Wq_x   = (const float*)d_in[3];
  const float* Wk_x   = (const float*)d_in[4];
  const float* Wv_x   = (const float*)d_in[5];
  const float* Wq_h   = (const float*)d_in[6];
  const float* Wk_h   = (const float*)d_in[7];
  const float* Wv_h   = (const float*)d_in[8];
  const float* W_lstm = (const float*)d_in[9];
  const float* b_lstm = (const float*)d_in[10];

  float* out   = (float*)d_out;
  float* new_h = out;                 // [16,64,32,32]
  float* new_c = out + 1048576;       // [16,64,32,32]
  float* atten = out + 2097152;       // [16,1024,1024]

  // ws layout (ushort granularity)
  ushort* wsu = (ushort*)d_ws;
  ushort* qT  = wsu;                  //   524,288 ushort [b][n][32]
  ushort* kT  = wsu + 524288;         //   524,288
  ushort* vb  = wsu + 1048576;        // 1,048,576 [b][c][m]

  // scratch aliased into the atten output region (dead until attn2):
  ushort* Wb    = (ushort*)(atten + 8388608);   // conv weights, bytes [33.55M,35.2M)
  ushort* pad   = (ushort*)(atten + 9437184);   // padded conv input, [37.7M,43.1M)
  float*  h_mid = new_h;                        // lstm h lives in new_h slot

  dim3 blk(256);
  // ---- prep (independent of attn1): h tpose + pad ring zero + weight prepass
  prep_kernel<<<dim3(18, NB), blk, 0, stream>>>(h, W_lstm, pad, Wb);
  // ---- attention 1 on x (fused; scores never touch HBM) ----
  qkvproj_kernel<<<dim3(16, NB), blk, 0, stream>>>(x, Wq_x, Wk_x, Wv_x, qT, kT, vb);
  attn_fused_kernel<false><<<dim3(64, NB), blk, 0, stream>>>(
      qT, kT, vb, x, nullptr, nullptr, pad /*kh0 interior*/, 1.0f);
  // ---- conv-lstm (bf16 MFMA, barrier-free K-loop, fused LSTM epilogue) ----
  conv_lstm_kernel<<<dim3(16, 2, NB), blk, 0, stream>>>(pad, Wb, b_lstm, c, new_c, h_mid);
  // ---- attention 2 on h_mid (atten f32 is a real output) ----
  qkvproj_kernel<<<dim3(16, NB), blk, 0, stream>>>(h_mid, Wq_h, Wk_h, Wv_h, qT, kT, vb);
  attn_fused_kernel<true><<<dim3(64, NB), blk, 0, stream>>>(
      qT, kT, vb, h_mid, atten, new_h, nullptr, 2.0f);
}

// Round 20
// 121.337 us; speedup vs baseline: 1.4804x; 1.4804x over previous
//
#include <hip/hip_runtime.h>
#include <hip/hip_bf16.h>
#include <cstddef>
#include <cstdint>

// Problem constants: B=16, CIN=COUT=64, HID=32, H=W=32, K=5, PAD=2
#define NTOK 1024      // H*W
#define NB   16        // batch
#define NC   64        // channels (CIN == COUT)
#define NHID 32        // attention hidden

// padded conv input: pad[b][kh][36*36 px][64 c] bf16
#define PAD_BSTRIDE 165888   // 2*1296*64
#define PAD_KSTRIDE 82944    // 1296*64

typedef __attribute__((ext_vector_type(8))) short short8;   // 8 bf16 = 4 VGPR (MFMA A/B frag)
typedef __attribute__((ext_vector_type(4))) float f32x4;    // MFMA acc frag / native v4f

// round-to-nearest-even f32 -> bf16 (as raw ushort)
__device__ __forceinline__ ushort f2b(float f) {
  uint32_t u = __builtin_bit_cast(uint32_t, f);
  return (ushort)((u + 0x7FFFu + ((u >> 16) & 1u)) >> 16);
}
__device__ __forceinline__ float b2f(ushort u) {
  return __builtin_bit_cast(float, (uint32_t)u << 16);
}
// 8 consecutive f32 -> bf16x8 frag
__device__ __forceinline__ short8 ldw8(const float* __restrict__ p) {
  float4 f0 = *(const float4*)p, f1 = *(const float4*)(p + 4);
  short8 r;
  r[0] = (short)f2b(f0.x); r[1] = (short)f2b(f0.y);
  r[2] = (short)f2b(f0.z); r[3] = (short)f2b(f0.w);
  r[4] = (short)f2b(f1.x); r[5] = (short)f2b(f1.y);
  r[6] = (short)f2b(f1.z); r[7] = (short)f2b(f1.w);
  return r;
}
__device__ __forceinline__ float sigm(float x) { return 1.f / (1.f + __expf(-x)); }
__device__ __forceinline__ float tanh_fast(float x) {
  float e = __expf(2.f * x);
  return 1.f - 2.f / (e + 1.f);   // safe at +/-inf
}

// ---- PREP: fused {h transpose -> pad kh1 interior | pad ring zero | weight
// pre-pass}. Grid (18, NB): x<16 tpose blocks, x==16 ring-zero, x==17 wpre slice.
__global__ __launch_bounds__(256) void prep_kernel(
    const float* __restrict__ h, const float* __restrict__ W,
    ushort* __restrict__ pad, ushort* __restrict__ Wb) {
  __shared__ float tile[64][65];
  int bx = blockIdx.x, b = blockIdx.y, t = threadIdx.x;
  if (bx < 16) {
    int n0 = bx * 64;
    const float* s = h + (size_t)b * NC * NTOK;
#pragma unroll
    for (int r = 0; r < 4; ++r) {
      int c = r * 16 + (t >> 4);
      int nl = (t & 15) * 4;
      float4 v = *(const float4*)(s + (size_t)c * NTOK + n0 + nl);
      tile[c][nl] = v.x; tile[c][nl + 1] = v.y; tile[c][nl + 2] = v.z; tile[c][nl + 3] = v.w;
    }
    __syncthreads();
    int tok = t >> 2, c0 = (t & 3) * 16;
    __attribute__((aligned(16))) ushort tmp[16];
#pragma unroll
    for (int i = 0; i < 16; ++i) tmp[i] = f2b(tile[c0 + i][tok]);
    int gtok = n0 + tok;
    ushort* d = pad + (size_t)b * PAD_BSTRIDE + PAD_KSTRIDE +
                ((gtok >> 5) + 2) * 2304 + ((gtok & 31) + 2) * 64 + c0;
    *(uint4*)(d)     = *(const uint4*)(tmp);
    *(uint4*)(d + 8) = *(const uint4*)(tmp + 8);
  } else if (bx == 16) {
    // zero the 272-px ring of both kh windows for batch b
    ushort* pb = pad + (size_t)b * PAD_BSTRIDE;
    for (int i = t; i < 2 * 2176; i += 256) {   // 2176 = 272 px * 8 chunks
      int kh = i >= 2176;
      int j = i - kh * 2176;
      int r = j >> 3, e = j & 7;
      int row, col;
      if (r < 144) { int r2 = r / 36; row = (r2 < 2) ? r2 : r2 + 32; col = r - r2 * 36; }
      else { int rr = r - 144; row = 2 + (rr >> 2); int cm = rr & 3; col = (cm < 2) ? cm : cm + 32; }
      *(uint4*)(pb + (size_t)kh * PAD_KSTRIDE + (size_t)(row * 36 + col) * 64 + e * 8) =
          make_uint4(0u, 0u, 0u, 0u);
    }
  } else {
    // weight pre-pass slice: oc in [b*16, b*16+16), all 128 ic
    for (int i = t; i < 2048; i += 256) {
      int oc = b * 16 + (i >> 7), ic = i & 127;
      const float* src = W + ((size_t)oc * 128 + ic) * 25;
#pragma unroll
      for (int kk = 0; kk < 25; ++kk)
        Wb[((size_t)oc * 25 + kk) * 128 + ic] = f2b(src[kk]);
    }
  }
}

// ---- fused transpose + q,k,v projection via MFMA (reads f32 channel-major x).
__global__ __launch_bounds__(256) void qkvproj_kernel(
    const float* __restrict__ x, const float* __restrict__ Wq,
    const float* __restrict__ Wk, const float* __restrict__ Wv,
    ushort* __restrict__ qT, ushort* __restrict__ kT, ushort* __restrict__ vb) {
  __shared__ float tile[64][65];
  __shared__ ushort xb[64][72];
  __shared__ ushort sq[64][32], sk[64][32];
  int t = threadIdx.x, wave = t >> 6, lane = t & 63;
  int lo = lane & 15, lg = lane >> 4;
  int n0 = blockIdx.x * 64, b = blockIdx.y;
  const float* s = x + (size_t)b * NC * NTOK;
#pragma unroll
  for (int r = 0; r < 4; ++r) {
    int c = r * 16 + (t >> 4);
    int nl = (t & 15) * 4;
    float4 v = *(const float4*)(s + (size_t)c * NTOK + n0 + nl);
    tile[c][nl] = v.x; tile[c][nl + 1] = v.y; tile[c][nl + 2] = v.z; tile[c][nl + 3] = v.w;
  }
  __syncthreads();
  {
    int tok = t >> 2, c0 = (t & 3) * 16;
    __attribute__((aligned(16))) ushort tmp[16];
#pragma unroll
    for (int i = 0; i < 16; ++i) tmp[i] = f2b(tile[c0 + i][tok]);
    *(uint4*)(&xb[tok][c0])     = *(const uint4*)(tmp);
    *(uint4*)(&xb[tok][c0 + 8]) = *(const uint4*)(tmp + 8);
  }
  __syncthreads();
  const ushort* xrow = &xb[wave * 16 + lo][8 * lg];
  short8 a0 = *(const short8*)(xrow);
  short8 a1 = *(const short8*)(xrow + 32);
  f32x4 aq[2], ak[2];
#pragma unroll
  for (int dg = 0; dg < 2; ++dg) {
    short8 wq0 = ldw8(Wq + (size_t)(dg * 16 + lo) * NC + 8 * lg);
    short8 wq1 = ldw8(Wq + (size_t)(dg * 16 + lo) * NC + 32 + 8 * lg);
    short8 wk0 = ldw8(Wk + (size_t)(dg * 16 + lo) * NC + 8 * lg);
    short8 wk1 = ldw8(Wk + (size_t)(dg * 16 + lo) * NC + 32 + 8 * lg);
    f32x4 z = {0.f, 0.f, 0.f, 0.f};
    aq[dg] = __builtin_amdgcn_mfma_f32_16x16x32_bf16(a0, wq0, z, 0, 0, 0);
    aq[dg] = __builtin_amdgcn_mfma_f32_16x16x32_bf16(a1, wq1, aq[dg], 0, 0, 0);
    ak[dg] = __builtin_amdgcn_mfma_f32_16x16x32_bf16(a0, wk0, z, 0, 0, 0);
    ak[dg] = __builtin_amdgcn_mfma_f32_16x16x32_bf16(a1, wk1, ak[dg], 0, 0, 0);
  }
  f32x4 av[4];
#pragma unroll
  for (int g = 0; g < 4; ++g) {
    short8 wv0 = ldw8(Wv + (size_t)(g * 16 + lo) * NC + 8 * lg);
    short8 wv1 = ldw8(Wv + (size_t)(g * 16 + lo) * NC + 32 + 8 * lg);
    f32x4 z = {0.f, 0.f, 0.f, 0.f};
    av[g] = __builtin_amdgcn_mfma_f32_16x16x32_bf16(wv0, a0, z, 0, 0, 0);
    av[g] = __builtin_amdgcn_mfma_f32_16x16x32_bf16(wv1, a1, av[g], 0, 0, 0);
  }
#pragma unroll
  for (int dg = 0; dg < 2; ++dg)
#pragma unroll
    for (int r = 0; r < 4; ++r) {
      sq[wave * 16 + 4 * lg + r][dg * 16 + lo] = f2b(aq[dg][r]);
      sk[wave * 16 + 4 * lg + r][dg * 16 + lo] = f2b(ak[dg][r]);
    }
  ushort* vbase = vb + (size_t)b * NC * NTOK + n0 + wave * 16 + lo;
#pragma unroll
  for (int g = 0; g < 4; ++g)
#pragma unroll
    for (int r = 0; r < 4; ++r)
      vbase[(size_t)(g * 16 + lg * 4 + r) * NTOK] = f2b(av[g][r]);
  __syncthreads();
  int tok = t >> 2, d0 = (t & 3) * 8;
  size_t base = ((size_t)b * NTOK + n0 + tok) * NHID + d0;
  *(short8*)(qT + base) = *(const short8*)(&sq[tok][d0]);
  *(short8*)(kT + base) = *(const short8*)(&sk[tok][d0]);
}

// ---- FUSED attention: scores (MFMA) -> softmax -> S->bf16 LDS -> coalesced
// NONTEMPORAL atten write (ATTN2) -> PV (MFMA, 2-chain) -> residual epilogue.
#define SP 1048   // S-LDS pitch (ushorts): bank stride 12 -> <=2-way
template <bool ATTN2>
__global__ __launch_bounds__(256) void attn_fused_kernel(
    const ushort* __restrict__ qT, const ushort* __restrict__ kT,
    const ushort* __restrict__ vb, const float* __restrict__ resid,
    float* __restrict__ attnf, float* __restrict__ outf,
    ushort* __restrict__ outb_pad, float scale) {
  __shared__ ushort s_lds[16 * SP];
  __shared__ float wmax[4][16], wsum[4][16];
  int t = threadIdx.x, wave = t >> 6, lane = t & 63;
  int lo = lane & 15, lg = lane >> 4;
  int n0 = blockIdx.x * 16, b = blockIdx.y;
  int m0 = wave * 256;
  short8 a = *(const short8*)(qT + ((size_t)b * NTOK + n0 + lo) * NHID + 8 * lg);
  f32x4 acc[16];
#pragma unroll
  for (int j = 0; j < 16; ++j) {
    short8 bf = *(const short8*)(kT + ((size_t)b * NTOK + m0 + j * 16 + lo) * NHID + 8 * lg);
    f32x4 z = {0.f, 0.f, 0.f, 0.f};
    acc[j] = __builtin_amdgcn_mfma_f32_16x16x32_bf16(a, bf, z, 0, 0, 0);
  }
  float pm[4];
#pragma unroll
  for (int r = 0; r < 4; ++r) {
    float m = acc[0][r];
#pragma unroll
    for (int j = 1; j < 16; ++j) m = fmaxf(m, acc[j][r]);
#pragma unroll
    for (int off = 1; off < 16; off <<= 1) m = fmaxf(m, __shfl_xor(m, off, 64));
    pm[r] = m;
  }
  if (lo == 0)
#pragma unroll
    for (int r = 0; r < 4; ++r) wmax[wave][4 * lg + r] = pm[r];
  __syncthreads();
  float mr[4];
#pragma unroll
  for (int r = 0; r < 4; ++r)
    mr[r] = fmaxf(fmaxf(wmax[0][4 * lg + r], wmax[1][4 * lg + r]),
                  fmaxf(wmax[2][4 * lg + r], wmax[3][4 * lg + r]));
  float ps[4] = {0.f, 0.f, 0.f, 0.f};
#pragma unroll
  for (int j = 0; j < 16; ++j)
#pragma unroll
    for (int r = 0; r < 4; ++r) {
      float e = __expf(acc[j][r] - mr[r]);
      acc[j][r] = e;
      ps[r] += e;
    }
#pragma unroll
  for (int r = 0; r < 4; ++r)
#pragma unroll
    for (int off = 1; off < 16; off <<= 1) ps[r] += __shfl_xor(ps[r], off, 64);
  if (lo == 0)
#pragma unroll
    for (int r = 0; r < 4; ++r) wsum[wave][4 * lg + r] = ps[r];
  __syncthreads();
  float inv[4];
#pragma unroll
  for (int r = 0; r < 4; ++r)
    inv[r] = 1.f / (wsum[0][4 * lg + r] + wsum[1][4 * lg + r] +
                    wsum[2][4 * lg + r] + wsum[3][4 * lg + r]);
#pragma unroll
  for (int j = 0; j < 16; ++j)
#pragma unroll
    for (int r = 0; r < 4; ++r)
      s_lds[(4 * lg + r) * SP + m0 + j * 16 + lo] = f2b(acc[j][r] * inv[r]);
  __syncthreads();
  if constexpr (ATTN2) {
    // coalesced nontemporal f32 write (64MB stream, never re-read -> bypass L2)
    int ml = lane * 4;
    float* abase = attnf + ((size_t)b * NTOK + n0) * NTOK + m0;
#pragma unroll
    for (int n = 0; n < 16; ++n) {
      ushort4 sv = *(const ushort4*)(s_lds + n * SP + m0 + ml);
      f32x4 o = {b2f(sv.x), b2f(sv.y), b2f(sv.z), b2f(sv.w)};
      __builtin_nontemporal_store(o, (f32x4*)(abase + (size_t)n * NTOK + ml));
    }
  }
  int cb = wave * 16;
  const ushort* vbb = vb + ((size_t)b * NC + cb + lo) * NTOK;
  f32x4 acc2 = {0.f, 0.f, 0.f, 0.f}, acc3 = {0.f, 0.f, 0.f, 0.f};
  for (int ms = 0; ms < NTOK; ms += 64) {
    short8 af0 = *(const short8*)(s_lds + lo * SP + ms + 8 * lg);
    short8 bf0 = *(const short8*)(vbb + ms + 8 * lg);
    short8 af1 = *(const short8*)(s_lds + lo * SP + ms + 32 + 8 * lg);
    short8 bf1 = *(const short8*)(vbb + ms + 32 + 8 * lg);
    acc2 = __builtin_amdgcn_mfma_f32_16x16x32_bf16(af0, bf0, acc2, 0, 0, 0);
    acc3 = __builtin_amdgcn_mfma_f32_16x16x32_bf16(af1, bf1, acc3, 0, 0, 0);
  }
#pragma unroll
  for (int r = 0; r < 4; ++r) acc2[r] += acc3[r];
  int c = cb + lo;
  float4 rv = *(const float4*)(resid + ((size_t)b * NC + c) * NTOK + n0 + 4 * lg);
  float rvv[4] = {rv.x, rv.y, rv.z, rv.w};
  if constexpr (ATTN2) {
    float4 o;
    o.x = scale * (rvv[0] + acc2[0]); o.y = scale * (rvv[1] + acc2[1]);
    o.z = scale * (rvv[2] + acc2[2]); o.w = scale * (rvv[3] + acc2[3]);
    *(float4*)(outf + ((size_t)b * NC + c) * NTOK + n0 + 4 * lg) = o;
  } else {
#pragma unroll
    for (int r = 0; r < 4; ++r) {
      int tok = n0 + 4 * lg + r;
      float val = scale * (rvv[r] + acc2[r]);
      outb_pad[(size_t)b * PAD_BSTRIDE + ((tok >> 5) + 2) * 2304 +
               ((tok & 31) + 2) * 64 + c] = f2b(val);
    }
  }
}

// ---- FUSED conv + LSTM, 2 wg/CU (r11 proven config, 52us) + isolated T5
// setprio around the MFMA cluster. wg = 4 waves = 128 gate-rows (32 ch x 4
// gates, chh in grid) x 64 px. Wave: gate-quad of a 16-ch block x 32 px.
// K = 50 steps (25 taps x 2 kh) of 128x64ic A-tiles, dbuf, 1 barrier/step;
// B window (6x36x64ic, one kh) restaged once at the kh switch.
// Grid (16 pt, 2 chh, 16 b) = 512 wgs. LDS 71.7 KB -> 2 wg/CU.
#define AP 76
#define BP 76
__global__ __launch_bounds__(256, 2) void conv_lstm_kernel(
    const ushort* __restrict__ pad,   // [b][2][36*36][64] bf16
    const ushort* __restrict__ Wb,    // [256 oc][25 kk][128 ic] bf16
    const float* __restrict__ bias, const float* __restrict__ c_in,
    float* __restrict__ c_out, float* __restrict__ h_out) {
  __shared__ ushort ldsA[2][128 * AP];  // ping-pong [gate-row][64 ic]
  __shared__ ushort ldsB[216 * BP];     // [6 rows x 36 cols][64 ic], one kh
  int t = threadIdx.x;
  int lane = t & 63, lo = lane & 15, lg = lane >> 4;
  int wid = t >> 6, cb = wid & 1, ph = wid >> 1;   // cb: 16-ch block, ph: px row
  int pt = blockIdx.x, chh = blockIdx.y, b = blockIdx.z;
  const ushort* pb = pad + (size_t)b * PAD_BSTRIDE + (size_t)(pt * 2) * 2304;

  // stage B window for kh=0 (contiguous src, pre-padded zeros)
  for (int i = t; i < 1728; i += 256) {
    int pxw = i >> 3, ch8 = (i & 7) * 8;
    uint4 v = *(const uint4*)(pb + (size_t)pxw * 64 + ch8);
    *(uint4*)(ldsB + pxw * BP + ch8) = v;
  }

  // per-thread A staging: 4 x 16B chunks cover 128 rows x 64 ic.
  // row r: gate = r>>5, oc = gate*64 + chh*32 + (r&31)
  const ushort *wsrc0, *wsrc1, *wsrc2, *wsrc3;
  int adst0, adst1, adst2, adst3;
  {
    int i0 = t, i1 = 256 + t, i2 = 512 + t, i3 = 768 + t;
    int r0 = i0 >> 3, r1 = i1 >> 3, r2 = i2 >> 3, r3 = i3 >> 3;
    wsrc0 = Wb + (size_t)((r0 >> 5) * 64 + chh * 32 + (r0 & 31)) * 3200 + (i0 & 7) * 8;
    wsrc1 = Wb + (size_t)((r1 >> 5) * 64 + chh * 32 + (r1 & 31)) * 3200 + (i1 & 7) * 8;
    wsrc2 = Wb + (size_t)((r2 >> 5) * 64 + chh * 32 + (r2 & 31)) * 3200 + (i2 & 7) * 8;
    wsrc3 = Wb + (size_t)((r3 >> 5) * 64 + chh * 32 + (r3 & 31)) * 3200 + (i3 & 7) * 8;
    adst0 = r0 * AP + (i0 & 7) * 8;
    adst1 = r1 * AP + (i1 & 7) * 8;
    adst2 = r2 * AP + (i2 & 7) * 8;
    adst3 = r3 * AP + (i3 & 7) * 8;
  }
  // koff(s) = tap*128 + kh*64, s = kh*25 + tap
  uint4 w0 = *(const uint4*)(wsrc0);        // step 0
  uint4 w1 = *(const uint4*)(wsrc1);
  uint4 w2 = *(const uint4*)(wsrc2);
  uint4 w3 = *(const uint4*)(wsrc3);

  f32x4 acc[4][2];
#pragma unroll
  for (int i = 0; i < 4; ++i)
#pragma unroll
    for (int j = 0; j < 2; ++j) acc[i][j] = {0.f, 0.f, 0.f, 0.f};

  __syncthreads();            // B staged
  *(uint4*)(&ldsA[0][adst0]) = w0;
  *(uint4*)(&ldsA[0][adst1]) = w1;
  *(uint4*)(&ldsA[0][adst2]) = w2;
  *(uint4*)(&ldsA[0][adst3]) = w3;
  w0 = *(const uint4*)(wsrc0 + 128);        // step 1
  w1 = *(const uint4*)(wsrc1 + 128);
  w2 = *(const uint4*)(wsrc2 + 128);
  w3 = *(const uint4*)(wsrc3 + 128);
  __syncthreads();            // A0 ready

  for (int s = 0; s < 50; ++s) {
    int cur = s & 1;
    if (s < 49) {
      int nxt = cur ^ 1;
      *(uint4*)(&ldsA[nxt][adst0]) = w0;
      *(uint4*)(&ldsA[nxt][adst1]) = w1;
      *(uint4*)(&ldsA[nxt][adst2]) = w2;
      *(uint4*)(&ldsA[nxt][adst3]) = w3;
      int s2 = (s < 48) ? s + 2 : 49;
      int koff = (s2 < 25) ? s2 * 128 : (s2 - 25) * 128 + 64;
      w0 = *(const uint4*)(wsrc0 + koff);
      w1 = *(const uint4*)(wsrc1 + koff);
      w2 = *(const uint4*)(wsrc2 + koff);
      w3 = *(const uint4*)(wsrc3 + koff);
    }
    int kh = (s >= 25);
    int tap = s - kh * 25;
    int ky = tap / 5, kx = tap - 5 * ky;
    int bbase = (ky * 36 + kx) * BP;
    __builtin_amdgcn_s_setprio(1);
#pragma unroll
    for (int icc = 0; icc < 2; ++icc) {
      short8 af[4], bf[2];
#pragma unroll
      for (int i = 0; i < 4; ++i)   // i = gate; A row = gate*32 + cb*16 + lo
        af[i] = *(const short8*)(&ldsA[cur][(i * 32 + cb * 16 + lo) * AP + icc * 32 + 8 * lg]);
#pragma unroll
      for (int j = 0; j < 2; ++j)
        bf[j] = *(const short8*)(ldsB + bbase + (ph * 36 + j * 16 + lo) * BP + icc * 32 + 8 * lg);
#pragma unroll
      for (int i = 0; i < 4; ++i)
#pragma unroll
        for (int j = 0; j < 2; ++j)
          acc[i][j] = __builtin_amdgcn_mfma_f32_16x16x32_bf16(af[i], bf[j], acc[i][j], 0, 0, 0);
    }
    __builtin_amdgcn_s_setprio(0);
    __syncthreads();
    if (s == 24) {
      // restage B for kh=1 (reads of kh0 window all done at the barrier above)
      for (int i = t; i < 1728; i += 256) {
        int pxw = i >> 3, ch8 = (i & 7) * 8;
        uint4 v = *(const uint4*)(pb + PAD_KSTRIDE + (size_t)pxw * 64 + ch8);
        *(uint4*)(ldsB + pxw * BP + ch8) = v;
      }
      __syncthreads();
    }
  }

  // LSTM epilogue: thread holds gates i/f/o/g at (ch, p)
#pragma unroll
  for (int j = 0; j < 2; ++j)
#pragma unroll
    for (int r = 0; r < 4; ++r) {
      int ch = chh * 32 + cb * 16 + lg * 4 + r;
      int p = pt * 64 + ph * 32 + j * 16 + lo;
      size_t ci = ((size_t)b * NC + ch) * NTOK + p;
      float iv = sigm(acc[0][j][r] + bias[ch]);
      float fv = sigm(acc[1][j][r] + bias[64 + ch]);
      float ov = sigm(acc[2][j][r] + bias[128 + ch]);
      float gv = tanh_fast(acc[3][j][r] + bias[192 + ch]);
      float cn = fv * c_in[ci] + iv * gv;
      c_out[ci] = cn;
      h_out[ci] = ov * tanh_fast(cn);
    }
}

extern "C" void kernel_launch(void* const* d_in, const int* in_sizes, int n_in,
                              void* d_out, int out_size, void* d_ws, size_t ws_size,
                              hipStream_t stream) {
  const float* x      = (const float*)d_in[0];
  const float* h      = (const float*)d_in[1];
  const float* c      = (const float*)d_in[2];
  const float* Wq_x   = (const float*)d_in[3];
  const float* Wk_x   = (const float*)d_in[4];
  const float* Wv_x   = (const float*)d_in[5];
  const float* Wq_h   = (const float*)d_in[6];
  const float* Wk_h   = (const float*)d_in[7];
  const float* Wv_h   = (const float*)d_in[8];
  const float* W_lstm = (const float*)d_in[9];
  const float* b_lstm = (const float*)d_in[10];

  float* out   = (float*)d_out;
  float* new_h = out;                 // [16,64,32,32]
  float* new_c = out + 1048576;       // [16,64,32,32]
  float* atten = out + 2097152;       // [16,1024,1024]

  // ws layout (ushort granularity)
  ushort* wsu = (ushort*)d_ws;
  ushort* qT  = wsu;                  //   524,288 ushort [b][n][32]
  ushort* kT  = wsu + 524288;         //   524,288
  ushort* vb  = wsu + 1048576;        // 1,048,576 [b][c][m]

  // scratch aliased into the atten output region (dead until attn2):
  ushort* Wb    = (ushort*)(atten + 8388608);   // conv weights, bytes [33.55M,35.2M)
  ushort* pad   = (ushort*)(atten + 9437184);   // padded conv input, [37.7M,43.1M)
  float*  h_mid = new_h;                        // lstm h lives in new_h slot

  dim3 blk(256);
  // ---- prep (independent of attn1): h tpose + pad ring zero + weight prepass
  prep_kernel<<<dim3(18, NB), blk, 0, stream>>>(h, W_lstm, pad, Wb);
  // ---- attention 1 on x (fused; scores never touch HBM) ----
  qkvproj_kernel<<<dim3(16, NB), blk, 0, stream>>>(x, Wq_x, Wk_x, Wv_x, qT, kT, vb);
  attn_fused_kernel<false><<<dim3(64, NB), blk, 0, stream>>>(
      qT, kT, vb, x, nullptr, nullptr, pad /*kh0 interior*/, 1.0f);
  // ---- conv-lstm (bf16 MFMA, r11 proven config + setprio, fused LSTM) ----
  conv_lstm_kernel<<<dim3(16, 2, NB), blk, 0, stream>>>(pad, Wb, b_lstm, c, new_c, h_mid);
  // ---- attention 2 on h_mid (atten f32 is a real output) ----
  qkvproj_kernel<<<dim3(16, NB), blk, 0, stream>>>(h_mid, Wq_h, Wk_h, Wv_h, qT, kT, vb);
  attn_fused_kernel<true><<<dim3(64, NB), blk, 0, stream>>>(
      qT, kT, vb, h_mid, atten, new_h, nullptr, 2.0f);
}

// Round 21
// 117.896 us; speedup vs baseline: 1.5236x; 1.0292x over previous
//
#include <hip/hip_runtime.h>
#include <hip/hip_bf16.h>
#include <cstddef>
#include <cstdint>

// Problem constants: B=16, CIN=COUT=64, HID=32, H=W=32, K=5, PAD=2
#define NTOK 1024      // H*W
#define NB   16        // batch
#define NC   64        // channels (CIN == COUT)
#define NHID 32        // attention hidden

// padded conv input: pad[b][kh][36*36 px][64 c] bf16
#define PAD_BSTRIDE 165888   // 2*1296*64
#define PAD_KSTRIDE 82944    // 1296*64

typedef __attribute__((ext_vector_type(8))) short short8;   // 8 bf16 = 4 VGPR (MFMA A/B frag)
typedef __attribute__((ext_vector_type(4))) float f32x4;    // MFMA acc frag / native v4f

// round-to-nearest-even f32 -> bf16 (as raw ushort)
__device__ __forceinline__ ushort f2b(float f) {
  uint32_t u = __builtin_bit_cast(uint32_t, f);
  return (ushort)((u + 0x7FFFu + ((u >> 16) & 1u)) >> 16);
}
__device__ __forceinline__ float b2f(ushort u) {
  return __builtin_bit_cast(float, (uint32_t)u << 16);
}
// 8 consecutive f32 -> bf16x8 frag
__device__ __forceinline__ short8 ldw8(const float* __restrict__ p) {
  float4 f0 = *(const float4*)p, f1 = *(const float4*)(p + 4);
  short8 r;
  r[0] = (short)f2b(f0.x); r[1] = (short)f2b(f0.y);
  r[2] = (short)f2b(f0.z); r[3] = (short)f2b(f0.w);
  r[4] = (short)f2b(f1.x); r[5] = (short)f2b(f1.y);
  r[6] = (short)f2b(f1.z); r[7] = (short)f2b(f1.w);
  return r;
}
__device__ __forceinline__ float sigm(float x) { return 1.f / (1.f + __expf(-x)); }
__device__ __forceinline__ float tanh_fast(float x) {
  float e = __expf(2.f * x);
  return 1.f - 2.f / (e + 1.f);   // safe at +/-inf
}

// ---- qkv projection body (used by both the combined and plain kernels).
__device__ __forceinline__ void qkv_body(
    const float* __restrict__ x, const float* __restrict__ Wq,
    const float* __restrict__ Wk, const float* __restrict__ Wv,
    ushort* __restrict__ qT, ushort* __restrict__ kT, ushort* __restrict__ vb,
    int n0, int b, int t, float (*tile)[65], ushort (*xb)[72],
    ushort (*sq)[32], ushort (*sk)[32]) {
  int wave = t >> 6, lane = t & 63;
  int lo = lane & 15, lg = lane >> 4;
  const float* s = x + (size_t)b * NC * NTOK;
#pragma unroll
  for (int r = 0; r < 4; ++r) {
    int c = r * 16 + (t >> 4);
    int nl = (t & 15) * 4;
    float4 v = *(const float4*)(s + (size_t)c * NTOK + n0 + nl);
    tile[c][nl] = v.x; tile[c][nl + 1] = v.y; tile[c][nl + 2] = v.z; tile[c][nl + 3] = v.w;
  }
  __syncthreads();
  {
    int tok = t >> 2, c0 = (t & 3) * 16;
    __attribute__((aligned(16))) ushort tmp[16];
#pragma unroll
    for (int i = 0; i < 16; ++i) tmp[i] = f2b(tile[c0 + i][tok]);
    *(uint4*)(&xb[tok][c0])     = *(const uint4*)(tmp);
    *(uint4*)(&xb[tok][c0 + 8]) = *(const uint4*)(tmp + 8);
  }
  __syncthreads();
  const ushort* xrow = &xb[wave * 16 + lo][8 * lg];
  short8 a0 = *(const short8*)(xrow);
  short8 a1 = *(const short8*)(xrow + 32);
  f32x4 aq[2], ak[2];
#pragma unroll
  for (int dg = 0; dg < 2; ++dg) {
    short8 wq0 = ldw8(Wq + (size_t)(dg * 16 + lo) * NC + 8 * lg);
    short8 wq1 = ldw8(Wq + (size_t)(dg * 16 + lo) * NC + 32 + 8 * lg);
    short8 wk0 = ldw8(Wk + (size_t)(dg * 16 + lo) * NC + 8 * lg);
    short8 wk1 = ldw8(Wk + (size_t)(dg * 16 + lo) * NC + 32 + 8 * lg);
    f32x4 z = {0.f, 0.f, 0.f, 0.f};
    aq[dg] = __builtin_amdgcn_mfma_f32_16x16x32_bf16(a0, wq0, z, 0, 0, 0);
    aq[dg] = __builtin_amdgcn_mfma_f32_16x16x32_bf16(a1, wq1, aq[dg], 0, 0, 0);
    ak[dg] = __builtin_amdgcn_mfma_f32_16x16x32_bf16(a0, wk0, z, 0, 0, 0);
    ak[dg] = __builtin_amdgcn_mfma_f32_16x16x32_bf16(a1, wk1, ak[dg], 0, 0, 0);
  }
  f32x4 av[4];
#pragma unroll
  for (int g = 0; g < 4; ++g) {
    short8 wv0 = ldw8(Wv + (size_t)(g * 16 + lo) * NC + 8 * lg);
    short8 wv1 = ldw8(Wv + (size_t)(g * 16 + lo) * NC + 32 + 8 * lg);
    f32x4 z = {0.f, 0.f, 0.f, 0.f};
    av[g] = __builtin_amdgcn_mfma_f32_16x16x32_bf16(wv0, a0, z, 0, 0, 0);
    av[g] = __builtin_amdgcn_mfma_f32_16x16x32_bf16(wv1, a1, av[g], 0, 0, 0);
  }
#pragma unroll
  for (int dg = 0; dg < 2; ++dg)
#pragma unroll
    for (int r = 0; r < 4; ++r) {
      sq[wave * 16 + 4 * lg + r][dg * 16 + lo] = f2b(aq[dg][r]);
      sk[wave * 16 + 4 * lg + r][dg * 16 + lo] = f2b(ak[dg][r]);
    }
  ushort* vbase = vb + (size_t)b * NC * NTOK + n0 + wave * 16 + lo;
#pragma unroll
  for (int g = 0; g < 4; ++g)
#pragma unroll
    for (int r = 0; r < 4; ++r)
      vbase[(size_t)(g * 16 + lg * 4 + r) * NTOK] = f2b(av[g][r]);
  __syncthreads();
  int tok = t >> 2, d0 = (t & 3) * 8;
  size_t base = ((size_t)b * NTOK + n0 + tok) * NHID + d0;
  *(short8*)(qT + base) = *(const short8*)(&sq[tok][d0]);
  *(short8*)(kT + base) = *(const short8*)(&sk[tok][d0]);
}

// ---- COMBINED phase-1 kernel: qkvproj(x) + {h tpose | ring zero | wpre}.
// Grid (34, NB): bx<16 qkv, 16..31 h-tpose, 32 ring-zero, 33 wpre slice.
__global__ __launch_bounds__(256) void qkvprep_kernel(
    const float* __restrict__ x, const float* __restrict__ Wq,
    const float* __restrict__ Wk, const float* __restrict__ Wv,
    ushort* __restrict__ qT, ushort* __restrict__ kT, ushort* __restrict__ vb,
    const float* __restrict__ h, const float* __restrict__ W,
    ushort* __restrict__ pad, ushort* __restrict__ Wb) {
  __shared__ float tile[64][65];
  __shared__ ushort xb[64][72];
  __shared__ ushort sq[64][32], sk[64][32];
  int bx = blockIdx.x, b = blockIdx.y, t = threadIdx.x;
  if (bx < 16) {
    qkv_body(x, Wq, Wk, Wv, qT, kT, vb, bx * 64, b, t, tile, xb, sq, sk);
  } else if (bx < 32) {
    // transpose + convert h -> pad kh1 interior
    int n0 = (bx - 16) * 64;
    const float* s = h + (size_t)b * NC * NTOK;
#pragma unroll
    for (int r = 0; r < 4; ++r) {
      int c = r * 16 + (t >> 4);
      int nl = (t & 15) * 4;
      float4 v = *(const float4*)(s + (size_t)c * NTOK + n0 + nl);
      tile[c][nl] = v.x; tile[c][nl + 1] = v.y; tile[c][nl + 2] = v.z; tile[c][nl + 3] = v.w;
    }
    __syncthreads();
    int tok = t >> 2, c0 = (t & 3) * 16;
    __attribute__((aligned(16))) ushort tmp[16];
#pragma unroll
    for (int i = 0; i < 16; ++i) tmp[i] = f2b(tile[c0 + i][tok]);
    int gtok = n0 + tok;
    ushort* d = pad + (size_t)b * PAD_BSTRIDE + PAD_KSTRIDE +
                ((gtok >> 5) + 2) * 2304 + ((gtok & 31) + 2) * 64 + c0;
    *(uint4*)(d)     = *(const uint4*)(tmp);
    *(uint4*)(d + 8) = *(const uint4*)(tmp + 8);
  } else if (bx == 32) {
    // zero the 272-px ring of both kh windows for batch b
    ushort* pb = pad + (size_t)b * PAD_BSTRIDE;
    for (int i = t; i < 2 * 2176; i += 256) {   // 2176 = 272 px * 8 chunks
      int kh = i >= 2176;
      int j = i - kh * 2176;
      int r = j >> 3, e = j & 7;
      int row, col;
      if (r < 144) { int r2 = r / 36; row = (r2 < 2) ? r2 : r2 + 32; col = r - r2 * 36; }
      else { int rr = r - 144; row = 2 + (rr >> 2); int cm = rr & 3; col = (cm < 2) ? cm : cm + 32; }
      *(uint4*)(pb + (size_t)kh * PAD_KSTRIDE + (size_t)(row * 36 + col) * 64 + e * 8) =
          make_uint4(0u, 0u, 0u, 0u);
    }
  } else {
    // weight pre-pass slice: oc in [b*16, b*16+16), all 128 ic
    for (int i = t; i < 2048; i += 256) {
      int oc = b * 16 + (i >> 7), ic = i & 127;
      const float* src = W + ((size_t)oc * 128 + ic) * 25;
#pragma unroll
      for (int kk = 0; kk < 25; ++kk)
        Wb[((size_t)oc * 25 + kk) * 128 + ic] = f2b(src[kk]);
    }
  }
}

// ---- plain qkvproj (attn2 phase)
__global__ __launch_bounds__(256) void qkvproj_kernel(
    const float* __restrict__ x, const float* __restrict__ Wq,
    const float* __restrict__ Wk, const float* __restrict__ Wv,
    ushort* __restrict__ qT, ushort* __restrict__ kT, ushort* __restrict__ vb) {
  __shared__ float tile[64][65];
  __shared__ ushort xb[64][72];
  __shared__ ushort sq[64][32], sk[64][32];
  qkv_body(x, Wq, Wk, Wv, qT, kT, vb, blockIdx.x * 64, blockIdx.y, threadIdx.x,
           tile, xb, sq, sk);
}

// ---- FUSED attention: scores (MFMA) -> softmax -> S->bf16 LDS -> coalesced
// NONTEMPORAL atten write (ATTN2) -> PV (MFMA, 2-chain) -> residual epilogue.
#define SP 1048   // S-LDS pitch (ushorts): bank stride 12 -> <=2-way
template <bool ATTN2>
__global__ __launch_bounds__(256) void attn_fused_kernel(
    const ushort* __restrict__ qT, const ushort* __restrict__ kT,
    const ushort* __restrict__ vb, const float* __restrict__ resid,
    float* __restrict__ attnf, float* __restrict__ outf,
    ushort* __restrict__ outb_pad, float scale) {
  __shared__ ushort s_lds[16 * SP];
  __shared__ float wmax[4][16], wsum[4][16];
  int t = threadIdx.x, wave = t >> 6, lane = t & 63;
  int lo = lane & 15, lg = lane >> 4;
  int n0 = blockIdx.x * 16, b = blockIdx.y;
  int m0 = wave * 256;
  short8 a = *(const short8*)(qT + ((size_t)b * NTOK + n0 + lo) * NHID + 8 * lg);
  f32x4 acc[16];
#pragma unroll
  for (int j = 0; j < 16; ++j) {
    short8 bf = *(const short8*)(kT + ((size_t)b * NTOK + m0 + j * 16 + lo) * NHID + 8 * lg);
    f32x4 z = {0.f, 0.f, 0.f, 0.f};
    acc[j] = __builtin_amdgcn_mfma_f32_16x16x32_bf16(a, bf, z, 0, 0, 0);
  }
  float pm[4];
#pragma unroll
  for (int r = 0; r < 4; ++r) {
    float m = acc[0][r];
#pragma unroll
    for (int j = 1; j < 16; ++j) m = fmaxf(m, acc[j][r]);
#pragma unroll
    for (int off = 1; off < 16; off <<= 1) m = fmaxf(m, __shfl_xor(m, off, 64));
    pm[r] = m;
  }
  if (lo == 0)
#pragma unroll
    for (int r = 0; r < 4; ++r) wmax[wave][4 * lg + r] = pm[r];
  __syncthreads();
  float mr[4];
#pragma unroll
  for (int r = 0; r < 4; ++r)
    mr[r] = fmaxf(fmaxf(wmax[0][4 * lg + r], wmax[1][4 * lg + r]),
                  fmaxf(wmax[2][4 * lg + r], wmax[3][4 * lg + r]));
  float ps[4] = {0.f, 0.f, 0.f, 0.f};
#pragma unroll
  for (int j = 0; j < 16; ++j)
#pragma unroll
    for (int r = 0; r < 4; ++r) {
      float e = __expf(acc[j][r] - mr[r]);
      acc[j][r] = e;
      ps[r] += e;
    }
#pragma unroll
  for (int r = 0; r < 4; ++r)
#pragma unroll
    for (int off = 1; off < 16; off <<= 1) ps[r] += __shfl_xor(ps[r], off, 64);
  if (lo == 0)
#pragma unroll
    for (int r = 0; r < 4; ++r) wsum[wave][4 * lg + r] = ps[r];
  __syncthreads();
  float inv[4];
#pragma unroll
  for (int r = 0; r < 4; ++r)
    inv[r] = 1.f / (wsum[0][4 * lg + r] + wsum[1][4 * lg + r] +
                    wsum[2][4 * lg + r] + wsum[3][4 * lg + r]);
#pragma unroll
  for (int j = 0; j < 16; ++j)
#pragma unroll
    for (int r = 0; r < 4; ++r)
      s_lds[(4 * lg + r) * SP + m0 + j * 16 + lo] = f2b(acc[j][r] * inv[r]);
  __syncthreads();
  if constexpr (ATTN2) {
    // coalesced nontemporal f32 write (64MB stream, never re-read -> bypass L2)
    int ml = lane * 4;
    float* abase = attnf + ((size_t)b * NTOK + n0) * NTOK + m0;
#pragma unroll
    for (int n = 0; n < 16; ++n) {
      ushort4 sv = *(const ushort4*)(s_lds + n * SP + m0 + ml);
      f32x4 o = {b2f(sv.x), b2f(sv.y), b2f(sv.z), b2f(sv.w)};
      __builtin_nontemporal_store(o, (f32x4*)(abase + (size_t)n * NTOK + ml));
    }
  }
  int cb = wave * 16;
  const ushort* vbb = vb + ((size_t)b * NC + cb + lo) * NTOK;
  f32x4 acc2 = {0.f, 0.f, 0.f, 0.f}, acc3 = {0.f, 0.f, 0.f, 0.f};
  for (int ms = 0; ms < NTOK; ms += 64) {
    short8 af0 = *(const short8*)(s_lds + lo * SP + ms + 8 * lg);
    short8 bf0 = *(const short8*)(vbb + ms + 8 * lg);
    short8 af1 = *(const short8*)(s_lds + lo * SP + ms + 32 + 8 * lg);
    short8 bf1 = *(const short8*)(vbb + ms + 32 + 8 * lg);
    acc2 = __builtin_amdgcn_mfma_f32_16x16x32_bf16(af0, bf0, acc2, 0, 0, 0);
    acc3 = __builtin_amdgcn_mfma_f32_16x16x32_bf16(af1, bf1, acc3, 0, 0, 0);
  }
#pragma unroll
  for (int r = 0; r < 4; ++r) acc2[r] += acc3[r];
  int c = cb + lo;
  float4 rv = *(const float4*)(resid + ((size_t)b * NC + c) * NTOK + n0 + 4 * lg);
  float rvv[4] = {rv.x, rv.y, rv.z, rv.w};
  if constexpr (ATTN2) {
    float4 o;
    o.x = scale * (rvv[0] + acc2[0]); o.y = scale * (rvv[1] + acc2[1]);
    o.z = scale * (rvv[2] + acc2[2]); o.w = scale * (rvv[3] + acc2[3]);
    *(float4*)(outf + ((size_t)b * NC + c) * NTOK + n0 + 4 * lg) = o;
  } else {
#pragma unroll
    for (int r = 0; r < 4; ++r) {
      int tok = n0 + 4 * lg + r;
      float val = scale * (rvv[r] + acc2[r]);
      outb_pad[(size_t)b * PAD_BSTRIDE + ((tok >> 5) + 2) * 2304 +
               ((tok & 31) + 2) * 64 + c] = f2b(val);
    }
  }
}

// ---- FUSED conv + LSTM, 2 wg/CU (proven 52us config + setprio). wg = 4 waves
// = 128 gate-rows (32 ch x 4 gates, chh in grid) x 64 px.
// K = 50 steps (25 taps x 2 kh) of 128x64ic A-tiles, dbuf, 1 barrier/step;
// B window (6x36x64ic, one kh) restaged once at the kh switch.
// Grid (16 pt, 2 chh, 16 b) = 512 wgs. LDS 71.7 KB -> 2 wg/CU.
#define AP 76
#define BP 76
__global__ __launch_bounds__(256, 2) void conv_lstm_kernel(
    const ushort* __restrict__ pad,   // [b][2][36*36][64] bf16
    const ushort* __restrict__ Wb,    // [256 oc][25 kk][128 ic] bf16
    const float* __restrict__ bias, const float* __restrict__ c_in,
    float* __restrict__ c_out, float* __restrict__ h_out) {
  __shared__ ushort ldsA[2][128 * AP];  // ping-pong [gate-row][64 ic]
  __shared__ ushort ldsB[216 * BP];     // [6 rows x 36 cols][64 ic], one kh
  int t = threadIdx.x;
  int lane = t & 63, lo = lane & 15, lg = lane >> 4;
  int wid = t >> 6, cb = wid & 1, ph = wid >> 1;   // cb: 16-ch block, ph: px row
  int pt = blockIdx.x, chh = blockIdx.y, b = blockIdx.z;
  const ushort* pb = pad + (size_t)b * PAD_BSTRIDE + (size_t)(pt * 2) * 2304;

  // stage B window for kh=0 (contiguous src, pre-padded zeros)
  for (int i = t; i < 1728; i += 256) {
    int pxw = i >> 3, ch8 = (i & 7) * 8;
    uint4 v = *(const uint4*)(pb + (size_t)pxw * 64 + ch8);
    *(uint4*)(ldsB + pxw * BP + ch8) = v;
  }

  // per-thread A staging: 4 x 16B chunks cover 128 rows x 64 ic.
  // row r: gate = r>>5, oc = gate*64 + chh*32 + (r&31)
  const ushort *wsrc0, *wsrc1, *wsrc2, *wsrc3;
  int adst0, adst1, adst2, adst3;
  {
    int i0 = t, i1 = 256 + t, i2 = 512 + t, i3 = 768 + t;
    int r0 = i0 >> 3, r1 = i1 >> 3, r2 = i2 >> 3, r3 = i3 >> 3;
    wsrc0 = Wb + (size_t)((r0 >> 5) * 64 + chh * 32 + (r0 & 31)) * 3200 + (i0 & 7) * 8;
    wsrc1 = Wb + (size_t)((r1 >> 5) * 64 + chh * 32 + (r1 & 31)) * 3200 + (i1 & 7) * 8;
    wsrc2 = Wb + (size_t)((r2 >> 5) * 64 + chh * 32 + (r2 & 31)) * 3200 + (i2 & 7) * 8;
    wsrc3 = Wb + (size_t)((r3 >> 5) * 64 + chh * 32 + (r3 & 31)) * 3200 + (i3 & 7) * 8;
    adst0 = r0 * AP + (i0 & 7) * 8;
    adst1 = r1 * AP + (i1 & 7) * 8;
    adst2 = r2 * AP + (i2 & 7) * 8;
    adst3 = r3 * AP + (i3 & 7) * 8;
  }
  // koff(s) = tap*128 + kh*64, s = kh*25 + tap
  uint4 w0 = *(const uint4*)(wsrc0);        // step 0
  uint4 w1 = *(const uint4*)(wsrc1);
  uint4 w2 = *(const uint4*)(wsrc2);
  uint4 w3 = *(const uint4*)(wsrc3);

  f32x4 acc[4][2];
#pragma unroll
  for (int i = 0; i < 4; ++i)
#pragma unroll
    for (int j = 0; j < 2; ++j) acc[i][j] = {0.f, 0.f, 0.f, 0.f};

  __syncthreads();            // B staged
  *(uint4*)(&ldsA[0][adst0]) = w0;
  *(uint4*)(&ldsA[0][adst1]) = w1;
  *(uint4*)(&ldsA[0][adst2]) = w2;
  *(uint4*)(&ldsA[0][adst3]) = w3;
  w0 = *(const uint4*)(wsrc0 + 128);        // step 1
  w1 = *(const uint4*)(wsrc1 + 128);
  w2 = *(const uint4*)(wsrc2 + 128);
  w3 = *(const uint4*)(wsrc3 + 128);
  __syncthreads();            // A0 ready

  for (int s = 0; s < 50; ++s) {
    int cur = s & 1;
    if (s < 49) {
      int nxt = cur ^ 1;
      *(uint4*)(&ldsA[nxt][adst0]) = w0;
      *(uint4*)(&ldsA[nxt][adst1]) = w1;
      *(uint4*)(&ldsA[nxt][adst2]) = w2;
      *(uint4*)(&ldsA[nxt][adst3]) = w3;
      int s2 = (s < 48) ? s + 2 : 49;
      int koff = (s2 < 25) ? s2 * 128 : (s2 - 25) * 128 + 64;
      w0 = *(const uint4*)(wsrc0 + koff);
      w1 = *(const uint4*)(wsrc1 + koff);
      w2 = *(const uint4*)(wsrc2 + koff);
      w3 = *(const uint4*)(wsrc3 + koff);
    }
    int kh = (s >= 25);
    int tap = s - kh * 25;
    int ky = tap / 5, kx = tap - 5 * ky;
    int bbase = (ky * 36 + kx) * BP;
    __builtin_amdgcn_s_setprio(1);
#pragma unroll
    for (int icc = 0; icc < 2; ++icc) {
      short8 af[4], bf[2];
#pragma unroll
      for (int i = 0; i < 4; ++i)   // i = gate; A row = gate*32 + cb*16 + lo
        af[i] = *(const short8*)(&ldsA[cur][(i * 32 + cb * 16 + lo) * AP + icc * 32 + 8 * lg]);
#pragma unroll
      for (int j = 0; j < 2; ++j)
        bf[j] = *(const short8*)(ldsB + bbase + (ph * 36 + j * 16 + lo) * BP + icc * 32 + 8 * lg);
#pragma unroll
      for (int i = 0; i < 4; ++i)
#pragma unroll
        for (int j = 0; j < 2; ++j)
          acc[i][j] = __builtin_amdgcn_mfma_f32_16x16x32_bf16(af[i], bf[j], acc[i][j], 0, 0, 0);
    }
    __builtin_amdgcn_s_setprio(0);
    __syncthreads();
    if (s == 24) {
      // restage B for kh=1 (reads of kh0 window all done at the barrier above)
      for (int i = t; i < 1728; i += 256) {
        int pxw = i >> 3, ch8 = (i & 7) * 8;
        uint4 v = *(const uint4*)(pb + PAD_KSTRIDE + (size_t)pxw * 64 + ch8);
        *(uint4*)(ldsB + pxw * BP + ch8) = v;
      }
      __syncthreads();
    }
  }

  // LSTM epilogue: thread holds gates i/f/o/g at (ch, p)
#pragma unroll
  for (int j = 0; j < 2; ++j)
#pragma unroll
    for (int r = 0; r < 4; ++r) {
      int ch = chh * 32 + cb * 16 + lg * 4 + r;
      int p = pt * 64 + ph * 32 + j * 16 + lo;
      size_t ci = ((size_t)b * NC + ch) * NTOK + p;
      float iv = sigm(acc[0][j][r] + bias[ch]);
      float fv = sigm(acc[1][j][r] + bias[64 + ch]);
      float ov = sigm(acc[2][j][r] + bias[128 + ch]);
      float gv = tanh_fast(acc[3][j][r] + bias[192 + ch]);
      float cn = fv * c_in[ci] + iv * gv;
      c_out[ci] = cn;
      h_out[ci] = ov * tanh_fast(cn);
    }
}

extern "C" void kernel_launch(void* const* d_in, const int* in_sizes, int n_in,
                              void* d_out, int out_size, void* d_ws, size_t ws_size,
                              hipStream_t stream) {
  const float* x      = (const float*)d_in[0];
  const float* h      = (const float*)d_in[1];
  const float* c      = (const float*)d_in[2];
  const float* Wq_x   = (const float*)d_in[3];
  const float* Wk_x   = (const float*)d_in[4];
  const float* Wv_x   = (const float*)d_in[5];
  const float* Wq_h   = (const float*)d_in[6];
  const float* Wk_h   = (const float*)d_in[7];
  const float* Wv_h   = (const float*)d_in[8];
  const float* W_lstm = (const float*)d_in[9];
  const float* b_lstm = (const float*)d_in[10];

  float* out   = (float*)d_out;
  float* new_h = out;                 // [16,64,32,32]
  float* new_c = out + 1048576;       // [16,64,32,32]
  float* atten = out + 2097152;       // [16,1024,1024]

  // ws layout (ushort granularity)
  ushort* wsu = (ushort*)d_ws;
  ushort* qT  = wsu;                  //   524,288 ushort [b][n][32]
  ushort* kT  = wsu + 524288;         //   524,288
  ushort* vb  = wsu + 1048576;        // 1,048,576 [b][c][m]

  // scratch aliased into the atten output region (dead until attn2):
  ushort* Wb    = (ushort*)(atten + 8388608);   // conv weights, bytes [33.55M,35.2M)
  ushort* pad   = (ushort*)(atten + 9437184);   // padded conv input, [37.7M,43.1M)
  float*  h_mid = new_h;                        // lstm h lives in new_h slot

  dim3 blk(256);
  // ---- phase 1: qkvproj(x) merged with prep {h tpose | ring zero | wpre} ----
  qkvprep_kernel<<<dim3(34, NB), blk, 0, stream>>>(
      x, Wq_x, Wk_x, Wv_x, qT, kT, vb, h, W_lstm, pad, Wb);
  attn_fused_kernel<false><<<dim3(64, NB), blk, 0, stream>>>(
      qT, kT, vb, x, nullptr, nullptr, pad /*kh0 interior*/, 1.0f);
  // ---- conv-lstm (bf16 MFMA, proven config + setprio, fused LSTM) ----
  conv_lstm_kernel<<<dim3(16, 2, NB), blk, 0, stream>>>(pad, Wb, b_lstm, c, new_c, h_mid);
  // ---- attention 2 on h_mid (atten f32 is a real output) ----
  qkvproj_kernel<<<dim3(16, NB), blk, 0, stream>>>(h_mid, Wq_h, Wk_h, Wv_h, qT, kT, vb);
  attn_fused_kernel<true><<<dim3(64, NB), blk, 0, stream>>>(
      qT, kT, vb, h_mid, atten, new_h, nullptr, 2.0f);
}